// Round 20
// baseline (212.215 us; speedup 1.0000x reference)
//
#include <hip/hip_runtime.h>

#define TT 32768   // B*S tokens
#define S_LEN 1024
#define NBLK 512

typedef __attribute__((ext_vector_type(8))) short short8;
typedef __attribute__((ext_vector_type(16))) float f32x16;

// intermediates; fully overwritten each call -> deterministic.
__device__ __align__(16) short g_Qb[64 * 1024 * 8];  // [bh][q][8] bf16 (Q*QSCALE, 4 real + 4 pad)
__device__ __align__(16) short g_Kb[64 * 1024 * 8];  // [bh][k][8] bf16 padded
__device__ __align__(16) short g_Vt[64 * 4 * 1024];  // [bh][d][k] bf16 (V transposed)
__device__ __align__(16) float g_C[TT * 8];
// grid barrier state: invariant cnt==0 between calls; gen monotonic.
__device__ unsigned g_bar_cnt;
__device__ unsigned g_bar_gen;

// ---------------------------------------------------------------------------
// Compile-time Pauli-backpropagation term tables (validated on HW in r11).
// ---------------------------------------------------------------------------
struct PTerm { unsigned ymask, zonly, tmask; float sgn; };
struct OTab { PTerm t[128]; int n; unsigned amask; };

constexpr unsigned conjZring(unsigned a) {
    for (int q = 7; q >= 0; --q) {
        const int c = q, tt = (q + 1) & 7;
        if ((a >> tt) & 1u) a ^= (1u << c);
    }
    return a;
}
constexpr unsigned conjXring(unsigned b) {
    for (int q = 7; q >= 0; --q) {
        const int c = q, tt = (q + 1) & 7;
        if ((b >> c) & 1u) b ^= (1u << tt);
    }
    return b;
}
constexpr int popc8(unsigned v) { int n = 0; for (int i = 0; i < 8; ++i) n += (v >> i) & 1; return n; }

constexpr OTab build_tab(int i) {
    OTab o{};
    o.n = 0;
    const unsigned a1 = conjZring(1u << i);
    o.amask = a1;
    const unsigned a3 = conjZring(a1);
    unsigned T = a1;
    while (true) {
        const unsigned b3 = conjXring(T);
        if (!(b3 & ~a3)) {
            const int k = popc8(T) + popc8(b3);
            const int idx = (k & 1) ? 100000 : o.n;   // odd phase => compile error
            o.t[idx].ymask = b3;
            o.t[idx].zonly = a3 & ~b3;
            o.t[idx].tmask = T;
            o.t[idx].sgn = ((k >> 1) & 1) ? -1.f : 1.f;
            o.n++;
        }
        if (T == 0) break;
        T = (T - 1) & a1;
    }
    return o;
}

constexpr OTab g_tab[8] = {build_tab(0), build_tab(1), build_tab(2), build_tab(3),
                           build_tab(4), build_tab(5), build_tab(6), build_tab(7)};
static_assert(g_tab[0].n >= 1 && g_tab[0].n <= 128, "term count");
static_assert(g_tab[7].n >= 1 && g_tab[7].n <= 128, "term count");

template <int I>
__device__ __forceinline__ void coef_one(const float s1[8], const float c1[8], float* dst)
{
    constexpr OTab tb = g_tab[I];
#pragma unroll
    for (int k = 0; k < tb.n; ++k) {
        float c = tb.t[k].sgn;
#pragma unroll
        for (int q = 0; q < 8; ++q) {
            if ((tb.t[k].tmask >> q) & 1) c *= s1[q];
            else if ((tb.amask >> q) & 1) c *= c1[q];
        }
        dst[k] = c;
    }
}

template <int I>
__device__ __forceinline__ float eval_out(const float cs[8], const float sn[8],
                                          const float* coefI)
{
    constexpr OTab tb = g_tab[I];
    float acc = 0.f;
#pragma unroll
    for (int k = 0; k < tb.n; ++k) {
        float p = coefI[k];
#pragma unroll
        for (int q = 0; q < 8; ++q) {
            if ((tb.t[k].ymask >> q) & 1) p *= sn[q];
            else if ((tb.t[k].zonly >> q) & 1) p *= cs[q];
        }
        acc += p;
    }
    return acc;
}

__device__ __forceinline__ void eval_all(const float th[8],
                                         const float (*coef)[128],
                                         float ev[8])
{
    float cs[8], sn[8];
#pragma unroll
    for (int q = 0; q < 8; ++q) __sincosf(th[q], &sn[q], &cs[q]);
    ev[0] = eval_out<0>(cs, sn, coef[0]);
    ev[1] = eval_out<1>(cs, sn, coef[1]);
    ev[2] = eval_out<2>(cs, sn, coef[2]);
    ev[3] = eval_out<3>(cs, sn, coef[3]);
    ev[4] = eval_out<4>(cs, sn, coef[4]);
    ev[5] = eval_out<5>(cs, sn, coef[5]);
    ev[6] = eval_out<6>(cs, sn, coef[6]);
    ev[7] = eval_out<7>(cs, sn, coef[7]);
}

// Q pre-scaled by 0.5*log2(e): attention exponent uses native v_exp (exp2).
#define QSCALE 0.72134752044448170368f

__device__ __forceinline__ float fexp2(float s)
{
    float r;
    asm("v_exp_f32 %0, %1" : "=v"(r) : "v"(s));
    return r;
}

// f32 -> bf16 (RNE), dependency-free
__device__ __forceinline__ short f2bf(float f)
{
    unsigned u = __float_as_uint(f);
    unsigned r = (u + 0x7FFFu + ((u >> 16) & 1u)) >> 16;
    return (short)r;
}

// device-wide barrier (all NBLK blocks co-resident: 2 blocks/CU at 512 blocks)
__device__ __forceinline__ void grid_barrier()
{
    __syncthreads();
    if (threadIdx.x == 0) {
        __threadfence();   // release: drain our writes to the coherence point
        unsigned gen = __hip_atomic_load(&g_bar_gen, __ATOMIC_RELAXED, __HIP_MEMORY_SCOPE_AGENT);
        unsigned prev = __hip_atomic_fetch_add(&g_bar_cnt, 1u, __ATOMIC_ACQ_REL, __HIP_MEMORY_SCOPE_AGENT);
        if (prev == NBLK - 1) {
            __hip_atomic_store(&g_bar_cnt, 0u, __ATOMIC_RELAXED, __HIP_MEMORY_SCOPE_AGENT);
            __hip_atomic_store(&g_bar_gen, gen + 1u, __ATOMIC_RELEASE, __HIP_MEMORY_SCOPE_AGENT);
        } else {
            while (__hip_atomic_load(&g_bar_gen, __ATOMIC_ACQUIRE, __HIP_MEMORY_SCOPE_AGENT) == gen)
                __builtin_amdgcn_s_sleep(16);
        }
        __threadfence();   // acquire: invalidate stale cache lines
    }
    __syncthreads();
}

// ---------------------------------------------------------------------------
// ONE kernel: coef (per-block LDS) -> qkv -> [grid barrier] -> MFMA attention
// (r19-validated body) -> [grid barrier] -> output circuit.
// Eliminates 3 inter-kernel dependency edges (per-edge L2 writeback across
// 8 non-coherent XCD L2s + dispatch ramp was the ~35 us constant offset).
// ---------------------------------------------------------------------------
__global__ __launch_bounds__(256, 2) void fused_all(
    const float* __restrict__ x, const float* __restrict__ wq,
    const float* __restrict__ wk, const float* __restrict__ wv,
    const float* __restrict__ wc, float* __restrict__ out)
{
    __shared__ float sh_coef[4][8][128];
    int tid = threadIdx.x;

    // ---- phase 0: per-block coefficient table (no cross-block dependency) ----
    if (tid < 32) {
        int set = tid >> 3, i = tid & 7;
        const float* w = (set == 0) ? wq : (set == 1) ? wk : (set == 2) ? wv : wc;
        float s1[8], c1[8];
#pragma unroll
        for (int q = 0; q < 8; ++q) __sincosf(w[8 + q], &s1[q], &c1[q]);
        float* dst = &sh_coef[set][i][0];
        switch (i) {
            case 0: coef_one<0>(s1, c1, dst); break;
            case 1: coef_one<1>(s1, c1, dst); break;
            case 2: coef_one<2>(s1, c1, dst); break;
            case 3: coef_one<3>(s1, c1, dst); break;
            case 4: coef_one<4>(s1, c1, dst); break;
            case 5: coef_one<5>(s1, c1, dst); break;
            case 6: coef_one<6>(s1, c1, dst); break;
            case 7: coef_one<7>(s1, c1, dst); break;
        }
    }
    __syncthreads();

    // ---- phase 1: Q/K/V circuits, one token-circuit per thread ----
    {
        int gid = blockIdx.x * 256 + tid;          // < 131072; work = 98304
        if (gid < TT * 3) {
            int set = gid >> 15;                   // 0..2
            int t = gid & (TT - 1);
            const float* w = (set == 0) ? wq : (set == 1) ? wk : wv;
            float4 xa = ((const float4*)x)[t * 2];
            float4 xb = ((const float4*)x)[t * 2 + 1];
            float th[8] = {xa.x + w[0], xa.y + w[1], xa.z + w[2], xa.w + w[3],
                           xb.x + w[4], xb.y + w[5], xb.z + w[6], xb.w + w[7]};
            float ev[8];
            eval_all(th, sh_coef[set], ev);
            int b = t >> 10, s = t & 1023;
            if (set == 2) {
#pragma unroll
                for (int h = 0; h < 2; ++h)
#pragma unroll
                    for (int d = 0; d < 4; ++d)
                        g_Vt[((size_t)((b * 2 + h) * 4 + d)) * 1024 + s] = f2bf(ev[h * 4 + d]);
            } else {
                short* dst = (set == 0) ? g_Qb : g_Kb;
                float sc = (set == 0) ? QSCALE : 1.f;
#pragma unroll
                for (int h = 0; h < 2; ++h) {
                    short8 row;
                    row[0] = f2bf(ev[h * 4 + 0] * sc);
                    row[1] = f2bf(ev[h * 4 + 1] * sc);
                    row[2] = f2bf(ev[h * 4 + 2] * sc);
                    row[3] = f2bf(ev[h * 4 + 3] * sc);
                    row[4] = 0; row[5] = 0; row[6] = 0; row[7] = 0;
                    *(short8*)(dst + ((size_t)(b * 2 + h) * 1024 + s) * 8) = row;
                }
            }
        }
    }

    grid_barrier();

    // ---- phase 2: MFMA attention (r19-validated body; 1 wave = (bh,qblk)) ----
    {
        int lane = tid & 63;
        int gw = blockIdx.x * 4 + (tid >> 6);      // 0..2047
        int bh = gw >> 5, qblk = gw & 31;
        int l31 = lane & 31, hi = lane >> 5;

        short8 zero8 = {0, 0, 0, 0, 0, 0, 0, 0};
        short8 ones8 = {0x3F80, 0x3F80, 0x3F80, 0x3F80, 0x3F80, 0x3F80, 0x3F80, 0x3F80};

        short8 qf = zero8;
        if (lane < 32)
            qf = *(const short8*)(g_Qb + ((size_t)bh * 1024 + qblk * 32 + l31) * 8);

        f32x16 acc;
#pragma unroll
        for (int r = 0; r < 16; ++r) acc[r] = 0.f;

        for (int kc = 0; kc < 32; ++kc) {
            short8 kf = zero8;
            if (lane < 32)
                kf = *(const short8*)(g_Kb + ((size_t)bh * 1024 + kc * 32 + l31) * 8);

            f32x16 zc;
#pragma unroll
            for (int r = 0; r < 16; ++r) zc[r] = 0.f;
            f32x16 c1 = __builtin_amdgcn_mfma_f32_32x32x16_bf16(kf, qf, zc, 0, 0, 0);

            float p[16];
#pragma unroll
            for (int r = 0; r < 16; ++r) p[r] = fexp2(c1[r]);

            unsigned w0, w1, w2, w3, w4, w5, w6, w7;
            asm("v_cvt_pk_bf16_f32 %0, %1, %2" : "=v"(w0) : "v"(p[0]),  "v"(p[1]));
            asm("v_cvt_pk_bf16_f32 %0, %1, %2" : "=v"(w1) : "v"(p[2]),  "v"(p[3]));
            asm("v_cvt_pk_bf16_f32 %0, %1, %2" : "=v"(w2) : "v"(p[4]),  "v"(p[5]));
            asm("v_cvt_pk_bf16_f32 %0, %1, %2" : "=v"(w3) : "v"(p[6]),  "v"(p[7]));
            asm("v_cvt_pk_bf16_f32 %0, %1, %2" : "=v"(w4) : "v"(p[8]),  "v"(p[9]));
            asm("v_cvt_pk_bf16_f32 %0, %1, %2" : "=v"(w5) : "v"(p[10]), "v"(p[11]));
            asm("v_cvt_pk_bf16_f32 %0, %1, %2" : "=v"(w6) : "v"(p[12]), "v"(p[13]));
            asm("v_cvt_pk_bf16_f32 %0, %1, %2" : "=v"(w7) : "v"(p[14]), "v"(p[15]));
            asm("v_permlane32_swap_b32 %0, %1" : "+v"(w0), "+v"(w2));
            asm("v_permlane32_swap_b32 %0, %1" : "+v"(w1), "+v"(w3));
            asm("v_permlane32_swap_b32 %0, %1" : "+v"(w4), "+v"(w6));
            asm("v_permlane32_swap_b32 %0, %1" : "+v"(w5), "+v"(w7));

            union { unsigned u[4]; short8 s8; } ba, bb;
            ba.u[0] = w0; ba.u[1] = w1; ba.u[2] = w2; ba.u[3] = w3;
            bb.u[0] = w4; bb.u[1] = w5; bb.u[2] = w6; bb.u[3] = w7;

            short8 va = zero8, vb = zero8;
            if (l31 < 4) {
                const short* vp = g_Vt + ((size_t)bh * 4 + l31) * 1024 + kc * 32 + hi * 8;
                va = *(const short8*)(vp);
                vb = *(const short8*)(vp + 16);
            } else if (l31 == 4) {
                va = ones8;
                vb = ones8;
            }
            acc = __builtin_amdgcn_mfma_f32_32x32x16_bf16(va, ba.s8, acc, 0, 0, 0);
            acc = __builtin_amdgcn_mfma_f32_32x32x16_bf16(vb, bb.s8, acc, 0, 0, 0);
        }

        float t0 = acc[0], t1 = acc[0];
        asm("v_permlane32_swap_b32 %0, %1" : "+v"(t0), "+v"(t1));
        float den = t0 + t1 - acc[0];
        if (lane < 32) {
            float inv = 1.f / den;
            int b = bh >> 1, h = bh & 1;
            float* cp = g_C + ((size_t)b * 1024 + qblk * 32 + l31) * 8 + h * 4;
            cp[0] = acc[0] * inv;
            cp[1] = acc[1] * inv;
            cp[2] = acc[2] * inv;
            cp[3] = acc[3] * inv;
        }
    }

    grid_barrier();

    // ---- phase 3: output circuit; wave 0 of each block does 64 tokens ----
    if (tid < 64) {
        int t = blockIdx.x * 64 + tid;             // covers all 32768 exactly
        float4 ca = ((const float4*)g_C)[t * 2];
        float4 cb = ((const float4*)g_C)[t * 2 + 1];
        float th[8] = {ca.x + wc[0], ca.y + wc[1], ca.z + wc[2], ca.w + wc[3],
                       cb.x + wc[4], cb.y + wc[5], cb.z + wc[6], cb.w + wc[7]};
        float ev[8];
        eval_all(th, sh_coef[3], ev);
        ((float4*)out)[t * 2]     = make_float4(ev[0], ev[1], ev[2], ev[3]);
        ((float4*)out)[t * 2 + 1] = make_float4(ev[4], ev[5], ev[6], ev[7]);
    }
}

extern "C" void kernel_launch(void* const* d_in, const int* in_sizes, int n_in,
                              void* d_out, int out_size, void* d_ws, size_t ws_size,
                              hipStream_t stream)
{
    const float* x  = (const float*)d_in[0];
    const float* wq = (const float*)d_in[1];
    const float* wk = (const float*)d_in[2];
    const float* wv = (const float*)d_in[3];
    const float* wc = (const float*)d_in[4];

    fused_all<<<NBLK, 256, 0, stream>>>(x, wq, wk, wv, wc, (float*)d_out);
}

// Round 21
// 77.123 us; speedup vs baseline: 2.7516x; 2.7516x over previous
//
#include <hip/hip_runtime.h>

#define TT 32768   // B*S tokens
#define S_LEN 1024
#define NBLK 256

typedef __attribute__((ext_vector_type(8))) short short8;
typedef __attribute__((ext_vector_type(16))) float f32x16;

// intermediates; fully overwritten each call -> deterministic.
__device__ __align__(16) short g_Qb[64 * 1024 * 8];  // [bh][q][8] bf16 (Q*QSCALE, 4 real + 4 pad)
__device__ __align__(16) short g_Kb[64 * 1024 * 8];  // [bh][k][8] bf16 padded
__device__ __align__(16) short g_Vt[64 * 4 * 1024];  // [bh][d][k] bf16 (V transposed)
// barrier state: cnt returns to 0 after each use; gen monotonic (equality test only)
__device__ unsigned g_bar_cnt;
__device__ unsigned g_bar_gen;

// ---------------------------------------------------------------------------
// Compile-time Pauli-backpropagation term tables (validated on HW in r11).
// ---------------------------------------------------------------------------
struct PTerm { unsigned ymask, zonly, tmask; float sgn; };
struct OTab { PTerm t[128]; int n; unsigned amask; };

constexpr unsigned conjZring(unsigned a) {
    for (int q = 7; q >= 0; --q) {
        const int c = q, tt = (q + 1) & 7;
        if ((a >> tt) & 1u) a ^= (1u << c);
    }
    return a;
}
constexpr unsigned conjXring(unsigned b) {
    for (int q = 7; q >= 0; --q) {
        const int c = q, tt = (q + 1) & 7;
        if ((b >> c) & 1u) b ^= (1u << tt);
    }
    return b;
}
constexpr int popc8(unsigned v) { int n = 0; for (int i = 0; i < 8; ++i) n += (v >> i) & 1; return n; }

constexpr OTab build_tab(int i) {
    OTab o{};
    o.n = 0;
    const unsigned a1 = conjZring(1u << i);
    o.amask = a1;
    const unsigned a3 = conjZring(a1);
    unsigned T = a1;
    while (true) {
        const unsigned b3 = conjXring(T);
        if (!(b3 & ~a3)) {
            const int k = popc8(T) + popc8(b3);
            const int idx = (k & 1) ? 100000 : o.n;   // odd phase => compile error
            o.t[idx].ymask = b3;
            o.t[idx].zonly = a3 & ~b3;
            o.t[idx].tmask = T;
            o.t[idx].sgn = ((k >> 1) & 1) ? -1.f : 1.f;
            o.n++;
        }
        if (T == 0) break;
        T = (T - 1) & a1;
    }
    return o;
}

constexpr OTab g_tab[8] = {build_tab(0), build_tab(1), build_tab(2), build_tab(3),
                           build_tab(4), build_tab(5), build_tab(6), build_tab(7)};
static_assert(g_tab[0].n >= 1 && g_tab[0].n <= 128, "term count");
static_assert(g_tab[7].n >= 1 && g_tab[7].n <= 128, "term count");

template <int I>
__device__ __forceinline__ void coef_one(const float s1[8], const float c1[8], float* dst)
{
    constexpr OTab tb = g_tab[I];
#pragma unroll
    for (int k = 0; k < tb.n; ++k) {
        float c = tb.t[k].sgn;
#pragma unroll
        for (int q = 0; q < 8; ++q) {
            if ((tb.t[k].tmask >> q) & 1) c *= s1[q];
            else if ((tb.amask >> q) & 1) c *= c1[q];
        }
        dst[k] = c;
    }
}

template <int I>
__device__ __forceinline__ float eval_out(const float cs[8], const float sn[8],
                                          const float* coefI)
{
    constexpr OTab tb = g_tab[I];
    float acc = 0.f;
#pragma unroll
    for (int k = 0; k < tb.n; ++k) {
        float p = coefI[k];
#pragma unroll
        for (int q = 0; q < 8; ++q) {
            if ((tb.t[k].ymask >> q) & 1) p *= sn[q];
            else if ((tb.t[k].zonly >> q) & 1) p *= cs[q];
        }
        acc += p;
    }
    return acc;
}

__device__ __forceinline__ void eval_all(const float th[8],
                                         const float (*coef)[128],
                                         float ev[8])
{
    float cs[8], sn[8];
#pragma unroll
    for (int q = 0; q < 8; ++q) __sincosf(th[q], &sn[q], &cs[q]);
    ev[0] = eval_out<0>(cs, sn, coef[0]);
    ev[1] = eval_out<1>(cs, sn, coef[1]);
    ev[2] = eval_out<2>(cs, sn, coef[2]);
    ev[3] = eval_out<3>(cs, sn, coef[3]);
    ev[4] = eval_out<4>(cs, sn, coef[4]);
    ev[5] = eval_out<5>(cs, sn, coef[5]);
    ev[6] = eval_out<6>(cs, sn, coef[6]);
    ev[7] = eval_out<7>(cs, sn, coef[7]);
}

// Q pre-scaled by 0.5*log2(e): attention exponent uses native v_exp (exp2).
#define QSCALE 0.72134752044448170368f

__device__ __forceinline__ float fexp2(float s)
{
    float r;
    asm("v_exp_f32 %0, %1" : "=v"(r) : "v"(s));
    return r;
}

// f32 -> bf16 (RNE), dependency-free
__device__ __forceinline__ short f2bf(float f)
{
    unsigned u = __float_as_uint(f);
    unsigned r = (u + 0x7FFFu + ((u >> 16) & 1u)) >> 16;
    return (short)r;
}

// ---------------------------------------------------------------------------
// Contention-free device barrier. r20's failure: waiters ACQUIRE-polled ->
// per-poll cache maintenance x 511 blocks = coherence storm (VALUBusy 3.9%).
// Fix: RELAXED poll + s_sleep(64); exactly ONE acquire after gen flips.
// Arrival: one ACQ_REL fetch_add per block (release-sequence publishes
// phase-1 writes; leader's gen RELEASE + waiter's final ACQUIRE completes it).
// 256 blocks <= 256 CUs: co-residency guaranteed.
// ---------------------------------------------------------------------------
__device__ __forceinline__ void grid_barrier_once()
{
    __syncthreads();
    if (threadIdx.x == 0) {
        unsigned gen = __hip_atomic_load(&g_bar_gen, __ATOMIC_RELAXED, __HIP_MEMORY_SCOPE_AGENT);
        unsigned prev = __hip_atomic_fetch_add(&g_bar_cnt, 1u, __ATOMIC_ACQ_REL, __HIP_MEMORY_SCOPE_AGENT);
        if (prev == NBLK - 1u) {
            __hip_atomic_store(&g_bar_cnt, 0u, __ATOMIC_RELAXED, __HIP_MEMORY_SCOPE_AGENT);
            __hip_atomic_store(&g_bar_gen, gen + 1u, __ATOMIC_RELEASE, __HIP_MEMORY_SCOPE_AGENT);
        } else {
            unsigned g2;
            do {
                __builtin_amdgcn_s_sleep(64);
                g2 = __hip_atomic_load(&g_bar_gen, __ATOMIC_RELAXED, __HIP_MEMORY_SCOPE_AGENT);
            } while (g2 == gen);
            (void)__hip_atomic_load(&g_bar_gen, __ATOMIC_ACQUIRE, __HIP_MEMORY_SCOPE_AGENT);
        }
    }
    __syncthreads();
}

// ---------------------------------------------------------------------------
// ONE kernel, ONE barrier:
//   phase 0: per-block coef table (LDS)
//   phase 1: Q/K/V circuits (grid-stride, 98304 evals)
//   [barrier]
//   phase 2: MFMA attention (r19-validated body) run for BOTH heads of this
//            wave's (b, qblk), then the output circuit INLINE (token ctx is
//            lane-local once both heads are done) -> no g_C, no 2nd barrier.
// ---------------------------------------------------------------------------
__global__ __launch_bounds__(256) void fused_v2(
    const float* __restrict__ x, const float* __restrict__ wq,
    const float* __restrict__ wk, const float* __restrict__ wv,
    const float* __restrict__ wc, float* __restrict__ out)
{
    __shared__ float sh_coef[4][8][128];
    int tid = threadIdx.x;

    // ---- phase 0 ----
    if (tid < 32) {
        int set = tid >> 3, i = tid & 7;
        const float* w = (set == 0) ? wq : (set == 1) ? wk : (set == 2) ? wv : wc;
        float s1[8], c1[8];
#pragma unroll
        for (int q = 0; q < 8; ++q) __sincosf(w[8 + q], &s1[q], &c1[q]);
        float* dst = &sh_coef[set][i][0];
        switch (i) {
            case 0: coef_one<0>(s1, c1, dst); break;
            case 1: coef_one<1>(s1, c1, dst); break;
            case 2: coef_one<2>(s1, c1, dst); break;
            case 3: coef_one<3>(s1, c1, dst); break;
            case 4: coef_one<4>(s1, c1, dst); break;
            case 5: coef_one<5>(s1, c1, dst); break;
            case 6: coef_one<6>(s1, c1, dst); break;
            case 7: coef_one<7>(s1, c1, dst); break;
        }
    }
    __syncthreads();

    // ---- phase 1: Q/K/V circuits, grid-stride over 98304 evals ----
    for (int gid = blockIdx.x * 256 + tid; gid < TT * 3; gid += NBLK * 256) {
        int set = gid >> 15;                   // 0..2  (TT = 2^15)
        int t = gid & (TT - 1);
        const float* w = (set == 0) ? wq : (set == 1) ? wk : wv;
        float4 xa = ((const float4*)x)[t * 2];
        float4 xb = ((const float4*)x)[t * 2 + 1];
        float th[8] = {xa.x + w[0], xa.y + w[1], xa.z + w[2], xa.w + w[3],
                       xb.x + w[4], xb.y + w[5], xb.z + w[6], xb.w + w[7]};
        float ev[8];
        eval_all(th, sh_coef[set], ev);
        int b = t >> 10, s = t & 1023;
        if (set == 2) {
#pragma unroll
            for (int h = 0; h < 2; ++h)
#pragma unroll
                for (int d = 0; d < 4; ++d)
                    g_Vt[((size_t)((b * 2 + h) * 4 + d)) * 1024 + s] = f2bf(ev[h * 4 + d]);
        } else {
            short* dst = (set == 0) ? g_Qb : g_Kb;
            float sc = (set == 0) ? QSCALE : 1.f;
#pragma unroll
            for (int h = 0; h < 2; ++h) {
                short8 row;
                row[0] = f2bf(ev[h * 4 + 0] * sc);
                row[1] = f2bf(ev[h * 4 + 1] * sc);
                row[2] = f2bf(ev[h * 4 + 2] * sc);
                row[3] = f2bf(ev[h * 4 + 3] * sc);
                row[4] = 0; row[5] = 0; row[6] = 0; row[7] = 0;
                *(short8*)(dst + ((size_t)(b * 2 + h) * 1024 + s) * 8) = row;
            }
        }
    }

    grid_barrier_once();

    // ---- phase 2: attention (both heads) + inline output circuit ----
    {
        int lane = tid & 63;
        int gw = blockIdx.x * 4 + (tid >> 6);      // 0..1023
        int b = gw >> 5, qblk = gw & 31;
        int l31 = lane & 31, hi = lane >> 5;

        short8 zero8 = {0, 0, 0, 0, 0, 0, 0, 0};
        short8 ones8 = {0x3F80, 0x3F80, 0x3F80, 0x3F80, 0x3F80, 0x3F80, 0x3F80, 0x3F80};

        float ctx[2][4];   // per lane<32: ctx for token (b, qblk*32+l31), head h

#pragma unroll
        for (int h = 0; h < 2; ++h) {
            int bh = b * 2 + h;
            short8 qf = zero8;
            if (lane < 32)
                qf = *(const short8*)(g_Qb + ((size_t)bh * 1024 + qblk * 32 + l31) * 8);

            f32x16 acc;
#pragma unroll
            for (int r = 0; r < 16; ++r) acc[r] = 0.f;

            for (int kc = 0; kc < 32; ++kc) {
                short8 kf = zero8;
                if (lane < 32)
                    kf = *(const short8*)(g_Kb + ((size_t)bh * 1024 + kc * 32 + l31) * 8);

                f32x16 zc;
#pragma unroll
                for (int r = 0; r < 16; ++r) zc[r] = 0.f;
                f32x16 c1 = __builtin_amdgcn_mfma_f32_32x32x16_bf16(kf, qf, zc, 0, 0, 0);

                float p[16];
#pragma unroll
                for (int r = 0; r < 16; ++r) p[r] = fexp2(c1[r]);

                unsigned w0, w1, w2, w3, w4, w5, w6, w7;
                asm("v_cvt_pk_bf16_f32 %0, %1, %2" : "=v"(w0) : "v"(p[0]),  "v"(p[1]));
                asm("v_cvt_pk_bf16_f32 %0, %1, %2" : "=v"(w1) : "v"(p[2]),  "v"(p[3]));
                asm("v_cvt_pk_bf16_f32 %0, %1, %2" : "=v"(w2) : "v"(p[4]),  "v"(p[5]));
                asm("v_cvt_pk_bf16_f32 %0, %1, %2" : "=v"(w3) : "v"(p[6]),  "v"(p[7]));
                asm("v_cvt_pk_bf16_f32 %0, %1, %2" : "=v"(w4) : "v"(p[8]),  "v"(p[9]));
                asm("v_cvt_pk_bf16_f32 %0, %1, %2" : "=v"(w5) : "v"(p[10]), "v"(p[11]));
                asm("v_cvt_pk_bf16_f32 %0, %1, %2" : "=v"(w6) : "v"(p[12]), "v"(p[13]));
                asm("v_cvt_pk_bf16_f32 %0, %1, %2" : "=v"(w7) : "v"(p[14]), "v"(p[15]));
                asm("v_permlane32_swap_b32 %0, %1" : "+v"(w0), "+v"(w2));
                asm("v_permlane32_swap_b32 %0, %1" : "+v"(w1), "+v"(w3));
                asm("v_permlane32_swap_b32 %0, %1" : "+v"(w4), "+v"(w6));
                asm("v_permlane32_swap_b32 %0, %1" : "+v"(w5), "+v"(w7));

                union { unsigned u[4]; short8 s8; } ba, bb;
                ba.u[0] = w0; ba.u[1] = w1; ba.u[2] = w2; ba.u[3] = w3;
                bb.u[0] = w4; bb.u[1] = w5; bb.u[2] = w6; bb.u[3] = w7;

                short8 va = zero8, vb = zero8;
                if (l31 < 4) {
                    const short* vp = g_Vt + ((size_t)bh * 4 + l31) * 1024 + kc * 32 + hi * 8;
                    va = *(const short8*)(vp);
                    vb = *(const short8*)(vp + 16);
                } else if (l31 == 4) {
                    va = ones8;
                    vb = ones8;
                }
                acc = __builtin_amdgcn_mfma_f32_32x32x16_bf16(va, ba.s8, acc, 0, 0, 0);
                acc = __builtin_amdgcn_mfma_f32_32x32x16_bf16(vb, bb.s8, acc, 0, 0, 0);
            }

            // den: lanes>=32 hold row 4 in reg 0; swap-exchange, robust form
            float t0 = acc[0], t1 = acc[0];
            asm("v_permlane32_swap_b32 %0, %1" : "+v"(t0), "+v"(t1));
            float den = t0 + t1 - acc[0];
            float inv = 1.f / den;
            ctx[h][0] = acc[0] * inv;
            ctx[h][1] = acc[1] * inv;
            ctx[h][2] = acc[2] * inv;
            ctx[h][3] = acc[3] * inv;
        }

        // ---- inline output circuit: token ctx is now lane-local ----
        if (lane < 32) {
            int t = b * 1024 + qblk * 32 + l31;
            float th[8] = {ctx[0][0] + wc[0], ctx[0][1] + wc[1],
                           ctx[0][2] + wc[2], ctx[0][3] + wc[3],
                           ctx[1][0] + wc[4], ctx[1][1] + wc[5],
                           ctx[1][2] + wc[6], ctx[1][3] + wc[7]};
            float ev[8];
            eval_all(th, sh_coef[3], ev);
            ((float4*)out)[t * 2]     = make_float4(ev[0], ev[1], ev[2], ev[3]);
            ((float4*)out)[t * 2 + 1] = make_float4(ev[4], ev[5], ev[6], ev[7]);
        }
    }
}

extern "C" void kernel_launch(void* const* d_in, const int* in_sizes, int n_in,
                              void* d_out, int out_size, void* d_ws, size_t ws_size,
                              hipStream_t stream)
{
    const float* x  = (const float*)d_in[0];
    const float* wq = (const float*)d_in[1];
    const float* wk = (const float*)d_in[2];
    const float* wv = (const float*)d_in[3];
    const float* wc = (const float*)d_in[4];

    fused_v2<<<NBLK, 256, 0, stream>>>(x, wq, wk, wv, wc, (float*)d_out);
}